// Round 20
// baseline (241.673 us; speedup 1.0000x reference)
//
#include <hip/hip_runtime.h>
#include <hip/hip_bf16.h>

#define G 5
#define B 8
#define CIN 320
#define CIN_G 64
#define COUT 480
#define COUT_G 96
#define NPOS 15872
#define NSTAT (B*NPOS)
#define BN_EPS 1e-5f
#define KDIM 62
#define H2ROW 6144          // bf16 elems per (b,g,j) h2 row-block (96ch x 64k)

typedef float  f32x4 __attribute__((ext_vector_type(4)));
typedef float  f32x2 __attribute__((ext_vector_type(2)));
typedef __bf16 bf16x8 __attribute__((ext_vector_type(8)));
typedef __bf16 bf16x4 __attribute__((ext_vector_type(4)));

// ---------------- prep: W1,W2 -> bf16; Ltb[g][p][64k] transposed bf16 zero-padded;
//                  L column sums (stride-64 padded)
__global__ __launch_bounds__(256) void k_prep(
    const float* __restrict__ W1, const float* __restrict__ W2, const float* __restrict__ L,
    __bf16* __restrict__ W1b, __bf16* __restrict__ W2b, __bf16* __restrict__ Ltb,
    float* __restrict__ lcs)
{
    const int bx = blockIdx.x;
    if (bx < 300) {
        const int i = bx * 256 + threadIdx.x;
        if (i < 30720) W1b[i] = (__bf16)W1[i];
        else W2b[i - 30720] = (__bf16)W2[i - 30720];
    } else {
        const int g = bx - 300;
        for (int e = threadIdx.x; e < 4096; e += 256) {
            const int p = e >> 6, k = e & 63;
            Ltb[g * 4096 + e] = (__bf16)((p < KDIM && k < KDIM) ? L[(g * KDIM + k) * KDIM + p] : 0.f);
        }
        if (threadIdx.x < 64) {
            float s = 0.f;
            if (threadIdx.x < KDIM)
                for (int k = 0; k < KDIM; ++k) s += L[(g * KDIM + k) * KDIM + threadIdx.x];
            lcs[g * 64 + threadIdx.x] = s;
        }
    }
}

// ---------------- BN1 stats pass: conv1 to REGISTERS only (no h store), reduce stats.
__global__ __launch_bounds__(256) void k_stat1(
    const float* __restrict__ x, const __bf16* __restrict__ W1b,
    float* __restrict__ sum1, float* __restrict__ sq1)
{
    __shared__ __bf16 wl[COUT_G * 72];            // 13824 B
    __shared__ float st[COUT_G * 2];
    const int b = blockIdx.z, g = blockIdx.y;
    for (int i = threadIdx.x; i < 768; i += 256) {
        const int idx = i * 8, o = idx >> 6, c = idx & 63;
        *(bf16x8*)&wl[o * 72 + c] = *(const bf16x8*)&W1b[g * 6144 + idx];
    }
    if (threadIdx.x < COUT_G * 2) st[threadIdx.x] = 0.f;
    __syncthreads();

    const int wid = threadIdx.x >> 6, lane = threadIdx.x & 63;
    const int lg = lane >> 4, lr = lane & 15;
    const int jw = blockIdx.x * 4 + wid;          // wave's j row (0..255)
    const float* xb = x + ((size_t)b * CIN + g * CIN_G) * NPOS;

    f32x4 acc1[6][4];
#pragma unroll
    for (int mt = 0; mt < 6; ++mt)
#pragma unroll
        for (int nt = 0; nt < 4; ++nt) acc1[mt][nt] = (f32x4){0.f,0.f,0.f,0.f};

#pragma unroll
    for (int ks = 0; ks < 2; ++ks) {
        const int c0 = ks * 32 + lg * 8;
        bf16x8 af[6];
#pragma unroll
        for (int mt = 0; mt < 6; ++mt)
            af[mt] = *(const bf16x8*)&wl[(mt * 16 + lr) * 72 + c0];
#pragma unroll
        for (int nt = 0; nt < 4; ++nt) {
            const int kcol = nt * 16 + lr;
            bf16x8 bfv;
            if (kcol < KDIM) {
                const float* xp = xb + jw * KDIM + kcol;
#pragma unroll
                for (int i = 0; i < 8; ++i) bfv[i] = (__bf16)xp[(size_t)(c0 + i) * NPOS];
            } else {
#pragma unroll
                for (int i = 0; i < 8; ++i) bfv[i] = (__bf16)0.f;
            }
#pragma unroll
            for (int mt = 0; mt < 6; ++mt)
                acc1[mt][nt] = __builtin_amdgcn_mfma_f32_16x16x32_bf16(af[mt], bfv, acc1[mt][nt], 0, 0, 0);
        }
    }

    // stats: channel o = mt*16+lg*4+r, summed over nt and lr (pad cols are exact 0)
#pragma unroll
    for (int mt = 0; mt < 6; ++mt) {
#pragma unroll
        for (int r = 0; r < 4; ++r) {
            float s = 0.f, q = 0.f;
#pragma unroll
            for (int nt = 0; nt < 4; ++nt) {
                const float v = acc1[mt][nt][r];
                s += v; q += v * v;
            }
#pragma unroll
            for (int m = 1; m <= 8; m <<= 1) {
                s += __shfl_xor(s, m);
                q += __shfl_xor(q, m);
            }
            if (lr == 0) {
                atomicAdd(&st[(mt * 16 + lg * 4 + r) * 2], s);
                atomicAdd(&st[(mt * 16 + lg * 4 + r) * 2 + 1], q);
            }
        }
    }
    __syncthreads();
    if (threadIdx.x < COUT_G) {
        atomicAdd(&sum1[g * COUT_G + threadIdx.x], st[threadIdx.x * 2]);
        atomicAdd(&sq1[g * COUT_G + threadIdx.x], st[threadIdx.x * 2 + 1]);
    }
}

// ---------------- fused: recompute h=W1@x, BN1+ELU, conv2 -> h2 bf16 (dense ws); BN2 stats
// CHANGE vs R19: h2 stored to ws in per-(b,g,j) 12KB-contiguous blocks via LDS
// roundtrip (XOR-granule swizzled) -- 12 x 1KB-contiguous stores/wave instead of
// 24 stores of 16 x 8B segments at 63.5KB stride.
__global__ __launch_bounds__(256, 2) void k_fused(
    const float* __restrict__ x, const __bf16* __restrict__ W1b, const __bf16* __restrict__ W2b,
    const float* __restrict__ sum1, const float* __restrict__ sq1,
    const float* __restrict__ gamma1, const float* __restrict__ beta1,
    __bf16* __restrict__ h2ws, float* __restrict__ sum2, float* __restrict__ sq2)
{
    __shared__ __bf16 wl[COUT_G * 72];            // 13824 B
    __shared__ __bf16 ht[4 * 6144];               // 49152 B: per-wave tile (eh, then h2)
    __shared__ float a1l[96], b1l[96], st[192];
    const int b = blockIdx.z, g = blockIdx.y;
    for (int i = threadIdx.x; i < 768; i += 256) {
        const int idx = i * 8, o = idx >> 6, c = idx & 63;
        *(bf16x8*)&wl[o * 72 + c] = *(const bf16x8*)&W1b[g * 6144 + idx];
    }
    if (threadIdx.x < 96) {
        const int ch = g * 96 + threadIdx.x;
        const float invN = 1.f / (float)NSTAT;
        const float mean = sum1[ch] * invN;
        const float var  = sq1[ch] * invN - mean * mean;
        const float av = gamma1[ch] * rsqrtf(var + BN_EPS);
        a1l[threadIdx.x] = av;
        b1l[threadIdx.x] = beta1[ch] - mean * av;
    }
    if (threadIdx.x < 192) st[threadIdx.x] = 0.f;
    __syncthreads();

    const int wid = threadIdx.x >> 6, lane = threadIdx.x & 63;
    const int lg = lane >> 4, lr = lane & 15;
    const int jw = blockIdx.x * 4 + wid;          // wave's j row (0..255)
    const float* xb = x + ((size_t)b * CIN + g * CIN_G) * NPOS;
    char* htw = (char*)(ht + wid * 6144);

    // ---- phase 1: C1[o][pos] = W1 @ x ; BN1+ELU ; swizzled k-packed LDS write
    {
        f32x4 acc1[6][4];
#pragma unroll
        for (int mt = 0; mt < 6; ++mt)
#pragma unroll
            for (int nt = 0; nt < 4; ++nt) acc1[mt][nt] = (f32x4){0.f,0.f,0.f,0.f};

#pragma unroll
        for (int ks = 0; ks < 2; ++ks) {
            const int c0 = ks * 32 + lg * 8;
            bf16x8 af[6];
#pragma unroll
            for (int mt = 0; mt < 6; ++mt)
                af[mt] = *(const bf16x8*)&wl[(mt * 16 + lr) * 72 + c0];
#pragma unroll
            for (int nt = 0; nt < 4; ++nt) {
                const int kcol = nt * 16 + lr;
                bf16x8 bfv;
                if (kcol < KDIM) {
                    const float* xp = xb + jw * KDIM + kcol;
#pragma unroll
                    for (int i = 0; i < 8; ++i) bfv[i] = (__bf16)xp[(size_t)(c0 + i) * NPOS];
                } else {
#pragma unroll
                    for (int i = 0; i < 8; ++i) bfv[i] = (__bf16)0.f;
                }
#pragma unroll
                for (int mt = 0; mt < 6; ++mt)
                    acc1[mt][nt] = __builtin_amdgcn_mfma_f32_16x16x32_bf16(af[mt], bfv, acc1[mt][nt], 0, 0, 0);
            }
        }
#pragma unroll
        for (int mt = 0; mt < 6; ++mt) {
            const int o0 = mt * 16 + lg * 4;
            const int c8 = o0 >> 3;
            const int half = (o0 & 7) >> 2;
#pragma unroll
            for (int nt = 0; nt < 4; ++nt) {
                const int pl = nt * 16 + lr;
                bf16x4 pv;
#pragma unroll
                for (int r = 0; r < 4; ++r) {
                    const int o = o0 + r;
                    float t = a1l[o] * acc1[mt][nt][r] + b1l[o];
                    t = t > 0.f ? t : (__expf(t) - 1.f);
                    pv[r] = (__bf16)t;
                }
                *(bf16x4*)(htw + c8 * 1024 + (pl ^ ((c8 & 3) << 1)) * 16 + half * 8) = pv;
            }
        }
    }

    // ---- phase 2: acc2[k-tile][ch-tile] = eh @ W2^T
    f32x4 acc2[4][6];
#pragma unroll
    for (int mt = 0; mt < 4; ++mt)
#pragma unroll
        for (int nt = 0; nt < 6; ++nt) acc2[mt][nt] = (f32x4){0.f,0.f,0.f,0.f};

#pragma unroll
    for (int ks = 0; ks < 3; ++ks) {
        const int c0 = ks * 32 + lg * 8;
        const int c8r = ks * 4 + lg;
        bf16x8 a2[4];
#pragma unroll
        for (int mt = 0; mt < 4; ++mt) {
            a2[mt] = *(const bf16x8*)(htw + c8r * 1024 + ((mt * 16 + lr) ^ ((c8r & 3) << 1)) * 16);
            if (mt == 3 && lr >= 14) {            // pad pos 62,63 -> zero rows
#pragma unroll
                for (int i = 0; i < 8; ++i) a2[mt][i] = (__bf16)0.f;
            }
        }
        bf16x8 bw[6];
#pragma unroll
        for (int nt = 0; nt < 6; ++nt)
            bw[nt] = *(const bf16x8*)&W2b[((size_t)g * 96 + nt * 16 + lr) * 96 + c0];
#pragma unroll
        for (int mt = 0; mt < 4; ++mt)
#pragma unroll
            for (int nt = 0; nt < 6; ++nt)
                acc2[mt][nt] = __builtin_amdgcn_mfma_f32_16x16x32_bf16(a2[mt], bw[nt], acc2[mt][nt], 0, 0, 0);
    }
    // acc2[mt][nt][r] = h2[ch = nt*16+lr][k = mt*16+lg*4+r]  (k=62,63 exact zero)

    // ---- BN2 stats (register-only)
#pragma unroll
    for (int nt = 0; nt < 6; ++nt) {
        const int o2 = nt * 16 + lr;
        float s = 0.f, q = 0.f;
#pragma unroll
        for (int mt = 0; mt < 4; ++mt)
#pragma unroll
            for (int r = 0; r < 4; ++r) {
                const float v = acc2[mt][nt][r];
                s += v; q += v * v;
            }
        s += __shfl_xor(s, 16); q += __shfl_xor(q, 16);
        s += __shfl_xor(s, 32); q += __shfl_xor(q, 32);
        if (lane < 16) {
            atomicAdd(&st[o2 * 2], s);
            atomicAdd(&st[o2 * 2 + 1], q);
        }
    }

    // ---- h2 -> wave-private LDS tile (overwrites eh; all phase-2 reads done):
    // byte = ch*128 + ((granule ^ (ch&7)) << 4) | ((lg&1)<<3); granule = mt*2+(lg>>1)
    // write banks: 8 distinct x 2 lanes (2-way, free)
#pragma unroll
    for (int nt = 0; nt < 6; ++nt) {
        const int ch = nt * 16 + lr;
#pragma unroll
        for (int mt = 0; mt < 4; ++mt) {
            bf16x4 pv;
#pragma unroll
            for (int r = 0; r < 4; ++r) pv[r] = (__bf16)acc2[mt][nt][r];
            const int gr = (mt * 2 + (lg >> 1)) ^ (ch & 7);
            *(bf16x4*)(htw + ch * 128 + (gr << 4) + ((lg & 1) << 3)) = pv;
        }
    }
    // flush: 12 x 1KB-contiguous f32x4 stores (swizzle preserved in global; adj unswizzles)
    {
        char* dst = (char*)(h2ws + ((size_t)((b * G + g) * 256 + jw)) * H2ROW);
#pragma unroll
        for (int it = 0; it < 12; ++it)
            *(f32x4*)(dst + it * 1024 + lane * 16) = *(const f32x4*)(htw + it * 1024 + lane * 16);
    }

    __syncthreads();
    if (threadIdx.x < 96) {
        atomicAdd(&sum2[g * 96 + threadIdx.x], st[threadIdx.x * 2]);
        atomicAdd(&sq2[g * 96 + threadIdx.x], st[threadIdx.x * 2 + 1]);
    }
}

// ---------------- adjacency (MFMA, A=L^T, B=h2^T -> C[p][j]); h2 from ws, y to d_out
// CHANGE vs R19: h2 read from dense ws blocks (wave-uniform XOR unswizzle); no barrier
__global__ __launch_bounds__(256) void k_adj(
    float* __restrict__ y, const __bf16* __restrict__ h2ws, const __bf16* __restrict__ Ltb,
    const float* __restrict__ sum2, const float* __restrict__ sq2,
    const float* __restrict__ gamma2, const float* __restrict__ beta2,
    const float* __restrict__ lcs)
{
    __shared__ float yt[4][32 * KDIM];   // 31744 B: per-wave 32x62 f32 y half-tile
    const int ch = blockIdx.x, b = blockIdx.y;
    const int g = ch / COUT_G;
    const int chl = ch - g * COUT_G;     // 0..95
    const int s = b * COUT + ch;

    const int wid = threadIdx.x >> 6, lane = threadIdx.x & 63;
    const int lg = lane >> 4, lr = lane & 15;
    const int j0 = wid * 64;
    const size_t rbase = (size_t)((b * G + g) * 256) * H2ROW + chl * 64;

    // h2 frags: row = j0+nt*16+lr (stride H2ROW), k-granule unswizzled by ch&7 (uniform)
    bf16x8 bt[4][2];
#pragma unroll
    for (int nt = 0; nt < 4; ++nt)
#pragma unroll
        for (int ks = 0; ks < 2; ++ks) {
            const int gr = ((ks * 4 + lg) ^ (chl & 7));
            bt[nt][ks] = *(const bf16x8*)&h2ws[rbase + (size_t)(j0 + nt * 16 + lr) * H2ROW + gr * 8];
        }

    bf16x8 lt[4][2];
#pragma unroll
    for (int mt = 0; mt < 4; ++mt)
#pragma unroll
        for (int ks = 0; ks < 2; ++ks)
            lt[mt][ks] = *(const bf16x8*)&Ltb[g * 4096 + (mt * 16 + lr) * 64 + ks * 32 + lg * 8];

    // BN2 coefs inline (uniform per block)
    const float invN = 1.f / (float)NSTAT;
    const float mean = sum2[ch] * invN;
    const float var  = sq2[ch] * invN - mean * mean;
    const float av = gamma2[ch] * rsqrtf(var + BN_EPS);
    const float bv = beta2[ch] - mean * av;

    f32x4 acc[4][4];
#pragma unroll
    for (int mt = 0; mt < 4; ++mt)
#pragma unroll
        for (int nt = 0; nt < 4; ++nt) acc[mt][nt] = (f32x4){0.f,0.f,0.f,0.f};

#pragma unroll
    for (int ks = 0; ks < 2; ++ks)
#pragma unroll
        for (int nt = 0; nt < 4; ++nt)
#pragma unroll
            for (int mt = 0; mt < 4; ++mt)
                acc[mt][nt] = __builtin_amdgcn_mfma_f32_16x16x32_bf16(lt[mt][ks], bt[nt][ks], acc[mt][nt], 0, 0, 0);

    f32x4 lcv[4];
#pragma unroll
    for (int mt = 0; mt < 4; ++mt)
        lcv[mt] = *(const f32x4*)&lcs[g * 64 + mt * 16 + lg * 4];

    float* ytw = yt[wid];
    // two halves: compute 32 rows into LDS, flush as contiguous 1KB/instr f32x4 stream
#pragma unroll
    for (int half = 0; half < 2; ++half) {
#pragma unroll
        for (int nth = 0; nth < 2; ++nth) {
            const int nt = half * 2 + nth;
            const int row = nth * 16 + lr;       // 0..31 within half
#pragma unroll
            for (int mt = 0; mt < 4; ++mt) {
                const int p0 = mt * 16 + lg * 4;
                f32x2 v0 = { av * acc[mt][nt][0] + bv * lcv[mt][0],
                             av * acc[mt][nt][1] + bv * lcv[mt][1] };
                *(f32x2*)&ytw[row * KDIM + p0] = v0;
                if (p0 < 60) {
                    f32x2 v1 = { av * acc[mt][nt][2] + bv * lcv[mt][2],
                                 av * acc[mt][nt][3] + bv * lcv[mt][3] };
                    *(f32x2*)&ytw[row * KDIM + p0 + 2] = v1;
                }
            }
        }
        float* yg = y + (size_t)s * NPOS + (j0 + half * 32) * KDIM;
#pragma unroll
        for (int it = 0; it < 8; ++it) {
            const int idx = it * 64 + lane;
            if (idx < 496)
                *(f32x4*)&yg[idx * 4] = *(const f32x4*)&ytw[idx * 4];
        }
    }
}

extern "C" void kernel_launch(void* const* d_in, const int* in_sizes, int n_in,
                              void* d_out, int out_size, void* d_ws, size_t ws_size,
                              hipStream_t stream)
{
    const float* x      = (const float*)d_in[0];
    const float* L      = (const float*)d_in[1];
    const float* W1     = (const float*)d_in[2];
    const float* W2     = (const float*)d_in[3];
    const float* gamma1 = (const float*)d_in[4];
    const float* beta1  = (const float*)d_in[5];
    const float* gamma2 = (const float*)d_in[6];
    const float* beta2  = (const float*)d_in[7];
    float* y = (float*)d_out;

    float* ws   = (float*)d_ws;
    float* sum1 = ws;            float* sq1 = ws + 480;
    float* sum2 = ws + 960;      float* sq2 = ws + 1440;
    float* lcs  = ws + 1920;     // 5*64 (stride-64 padded)
    __bf16* W1b  = (__bf16*)(ws + 2240);   // 30720 bf16
    __bf16* W2b  = (__bf16*)(ws + 17600);  // 46080 bf16
    __bf16* Ltb  = (__bf16*)(ws + 40640);  // 20480 bf16
    __bf16* h2ws = (__bf16*)(ws + 50880);  // 8*5*256*6144 bf16 = 125.8 MB

    // zero sum1+sq1+sum2+sq2 (contiguous 1920 floats)
    hipMemsetAsync(ws, 0, 1920 * sizeof(float), stream);

    k_prep <<<305, 256, 0, stream>>>(W1, W2, L, W1b, W2b, Ltb, lcs);
    k_stat1<<<dim3(64, G, B), 256, 0, stream>>>(x, W1b, sum1, sq1);
    k_fused<<<dim3(64, G, B), 256, 0, stream>>>(x, W1b, W2b, sum1, sq1, gamma1, beta1,
                                                h2ws, sum2, sq2);
    k_adj  <<<dim3(COUT, B), 256, 0, stream>>>(y, h2ws, Ltb, sum2, sq2, gamma2, beta2, lcs);
}